// Round 2
// baseline (614.529 us; speedup 1.0000x reference)
//
#include <hip/hip_runtime.h>

typedef unsigned short ushort_t;
typedef __attribute__((ext_vector_type(8))) __bf16 bf16x8;
typedef __attribute__((ext_vector_type(4))) float f32x4;
typedef __attribute__((ext_vector_type(4))) int i32x4;
typedef __attribute__((ext_vector_type(4))) unsigned short u16x4;

__device__ __forceinline__ float bf2f(ushort_t u) {
  union { unsigned u32; float f; } c; c.u32 = ((unsigned)u) << 16; return c.f;
}
__device__ __forceinline__ ushort_t f2bf(float f) {
  union { float f; unsigned u32; } c; c.f = f;
  unsigned u = c.u32;
  u += 0x7fffu + ((u >> 16) & 1u);   // round-to-nearest-even (no NaNs here)
  return (ushort_t)(u >> 16);
}

__device__ __forceinline__ void gload_lds16(const void* g, void* l) {
  __builtin_amdgcn_global_load_lds(
      (const __attribute__((address_space(1))) void*)g,
      (__attribute__((address_space(3))) void*)l,
      16, 0, 0);
}

// ---------------------------------------------------------------------------
// 128x128 bf16 NT GEMM: C[m,n] = scale * sum_k A[m,k]*B[n,k] (+bias, relu)
// EPI: 0 none, 1 +bias, 2 +bias+relu.  CSKIP: skip bx > by (causal scores).
// CKLIM: K limited to (by+1)*128 (causal PV).
// BM=BN=128, BK=32, 4 waves (2x2), 16x16x32 MFMA, 4x4 frags/wave (m97 structure).
// ---------------------------------------------------------------------------
template<int EPI, bool CSKIP, bool CKLIM>
__global__ __launch_bounds__(256) void gemm128(
    const ushort_t* __restrict__ A, int lda, long bsA,
    const ushort_t* __restrict__ B, int ldb, long bsB,
    ushort_t* __restrict__ C, int ldc, long bsC,
    const float* __restrict__ bias, float scale, int K)
{
  const int bx = blockIdx.x, by = blockIdx.y, bz = blockIdx.z;
  if (CSKIP && bx > by) return;
  const int kend = CKLIM ? ((by + 1) << 7) : K;

  __shared__ __attribute__((aligned(16))) ushort_t As[128 * 32];
  __shared__ __attribute__((aligned(16))) ushort_t Bs[128 * 32];

  const int tid = threadIdx.x;
  const int wave = tid >> 6, lane = tid & 63;
  const int wm = ((wave >> 1) & 1) << 6;
  const int wn = (wave & 1) << 6;
  const long m0 = (long)by << 7, n0 = (long)bx << 7;

  const ushort_t* Ab = A + bz * bsA;
  const ushort_t* Bb = B + bz * bsB;

  f32x4 acc[4][4] = {};

  const int srow = tid >> 2;            // staging row (0..63), +64 on 2nd issue
  const int scolb = (tid & 3) << 4;     // byte col within 64B row
  char* lA = (char*)As + (wave << 10);  // wave-uniform LDS base (+lane*16 by HW)
  char* lB = (char*)Bs + (wave << 10);

  for (int k0 = 0; k0 < kend; k0 += 32) {
    const char* gA = (const char*)Ab + (((m0 + srow) * lda + k0) << 1) + scolb;
    const char* gB = (const char*)Bb + (((n0 + srow) * ldb + k0) << 1) + scolb;
    gload_lds16(gA, lA);
    gload_lds16(gA + ((long)lda << 7), lA + 4096);   // rows +64
    gload_lds16(gB, lB);
    gload_lds16(gB + ((long)ldb << 7), lB + 4096);
    __syncthreads();

    const int kc = (lane >> 4) << 4;   // 16B k-chunk per lane group
    const int fr = lane & 15;
    bf16x8 af[4], bfr[4];
#pragma unroll
    for (int i = 0; i < 4; ++i) {
      af[i]  = *(const bf16x8*)((const char*)As + (wm + i * 16 + fr) * 64 + kc);
      bfr[i] = *(const bf16x8*)((const char*)Bs + (wn + i * 16 + fr) * 64 + kc);
    }
#pragma unroll
    for (int i = 0; i < 4; ++i)
#pragma unroll
      for (int j = 0; j < 4; ++j)
        acc[i][j] = __builtin_amdgcn_mfma_f32_16x16x32_bf16(af[i], bfr[j], acc[i][j], 0, 0, 0);
    __syncthreads();
  }

  ushort_t* Cb = C + bz * bsC;
  const int cm = (lane >> 4) << 2;
  const int cn = lane & 15;
#pragma unroll
  for (int i = 0; i < 4; ++i)
#pragma unroll
    for (int j = 0; j < 4; ++j) {
      const long gm = m0 + wm + i * 16 + cm;
      const long gn = n0 + wn + j * 16 + cn;
      float bv = 0.f;
      if constexpr (EPI >= 1) bv = bias[gn];
#pragma unroll
      for (int r = 0; r < 4; ++r) {
        float v = acc[i][j][r] * scale + bv;
        if constexpr (EPI == 2) v = fmaxf(v, 0.f);
        Cb[(gm + r) * ldc + gn] = f2bf(v);
      }
    }
}

// ---------------------------------------------------------------------------
// 64x64 bf16 transpose: Vt[d][s] = V[s][d]
// ---------------------------------------------------------------------------
__global__ __launch_bounds__(256) void transpose_bf16(
    const ushort_t* __restrict__ V, int ldv, long bsV,
    ushort_t* __restrict__ Vt, int ldt, long bsT)
{
  __shared__ __attribute__((aligned(16))) ushort_t tile[64][72]; // 144B rows (16B-aligned)
  const int bz = blockIdx.z;
  const ushort_t* Vb = V + bz * bsV;
  ushort_t* Tb = Vt + bz * bsT;
  const long s0 = (long)blockIdx.y << 6;
  const long d0 = (long)blockIdx.x << 6;
  const int tid = threadIdx.x;
  const int r = tid >> 3, c = tid & 7;
#pragma unroll
  for (int h = 0; h < 2; ++h) {
    const int rr = r + h * 32;
    i32x4 v = *(const i32x4*)(Vb + (s0 + rr) * ldv + d0 + c * 8);
    *(i32x4*)&tile[rr][c * 8] = v;
  }
  __syncthreads();
#pragma unroll
  for (int h = 0; h < 2; ++h) {
    const int dr = r + h * 32;
    union { ushort_t u[8]; i32x4 v; } t;
#pragma unroll
    for (int j = 0; j < 8; ++j) t.u[j] = tile[c * 8 + j][dr];
    *(i32x4*)(Tb + (d0 + dr) * ldt + s0 + c * 8) = t.v;
  }
}

// ---------------------------------------------------------------------------
// Row softmax over s<=t (denominator over ALL s<=t; SIT mask applied AFTER),
// writes P (bf16) in place, zero-fills to next 128 boundary for the PV GEMM.
// ---------------------------------------------------------------------------
__global__ __launch_bounds__(256) void softmax_sit(ushort_t* __restrict__ S,
                                                   const float* __restrict__ sit)
{
  __shared__ float buf[2048];
  __shared__ float red[4];
  const long row = blockIdx.x;           // b*2048 + t
  const int b = (int)(row >> 11);
  const int t = (int)(row & 2047);
  ushort_t* Srow = S + (row << 11);
  const int tid = threadIdx.x;
  const int n = t + 1;

  float mloc = -3.0e38f;
  for (int i = tid; i < n; i += 256) {
    float v = bf2f(Srow[i]);
    buf[i] = v;
    mloc = fmaxf(mloc, v);
  }
#pragma unroll
  for (int o = 32; o > 0; o >>= 1) mloc = fmaxf(mloc, __shfl_down(mloc, o, 64));
  if ((tid & 63) == 0) red[tid >> 6] = mloc;
  __syncthreads();
  const float m = fmaxf(fmaxf(red[0], red[1]), fmaxf(red[2], red[3]));
  __syncthreads();

  float sloc = 0.f;
  for (int i = tid; i < n; i += 256) sloc += __expf(buf[i] - m);
#pragma unroll
  for (int o = 32; o > 0; o >>= 1) sloc += __shfl_down(sloc, o, 64);
  if ((tid & 63) == 0) red[tid >> 6] = sloc;
  __syncthreads();
  const float l = red[0] + red[1] + red[2] + red[3];

  float inv = 1.f / l;
  if (sit[row] == 0.f) inv = 0.f;         // row mask (keep_t)
  const float* sitb = sit + ((long)b << 11);
  const int rup = ((t >> 7) + 1) << 7;
  for (int i = tid; i < rup; i += 256) {
    float p = 0.f;
    if (i < n && sitb[i] != 0.f) p = __expf(buf[i] - m) * inv;
    Srow[i] = f2bf(p);
  }
}

// ---------------------------------------------------------------------------
// out = LN(xin + res) * g + b ; D = 1024, one block per row
// ---------------------------------------------------------------------------
template<bool RES_F32, bool OUT_F32>
__global__ __launch_bounds__(256) void resid_ln(
    const ushort_t* __restrict__ xin, const void* __restrict__ resv,
    const float* __restrict__ g, const float* __restrict__ be, void* __restrict__ outv)
{
  __shared__ float red[4];
  const long base = (long)blockIdx.x << 10;
  const int tid = threadIdx.x;
  const int i0 = tid << 2;

  const u16x4 xa = *(const u16x4*)(xin + base + i0);
  float v[4];
  if constexpr (RES_F32) {
    const float4 rv = *(const float4*)((const float*)resv + base + i0);
    v[0] = bf2f(xa.x) + rv.x; v[1] = bf2f(xa.y) + rv.y;
    v[2] = bf2f(xa.z) + rv.z; v[3] = bf2f(xa.w) + rv.w;
  } else {
    const u16x4 rb = *(const u16x4*)((const ushort_t*)resv + base + i0);
    v[0] = bf2f(xa.x) + bf2f(rb.x); v[1] = bf2f(xa.y) + bf2f(rb.y);
    v[2] = bf2f(xa.z) + bf2f(rb.z); v[3] = bf2f(xa.w) + bf2f(rb.w);
  }
  float s = v[0] + v[1] + v[2] + v[3];
#pragma unroll
  for (int o = 32; o > 0; o >>= 1) s += __shfl_down(s, o, 64);
  if ((tid & 63) == 0) red[tid >> 6] = s;
  __syncthreads();
  const float mu = (red[0] + red[1] + red[2] + red[3]) * (1.f / 1024.f);
  __syncthreads();
  float s2 = 0.f;
#pragma unroll
  for (int j = 0; j < 4; ++j) { const float d = v[j] - mu; s2 += d * d; }
#pragma unroll
  for (int o = 32; o > 0; o >>= 1) s2 += __shfl_down(s2, o, 64);
  if ((tid & 63) == 0) red[tid >> 6] = s2;
  __syncthreads();
  const float rstd = rsqrtf((red[0] + red[1] + red[2] + red[3]) * (1.f / 1024.f) + 1e-5f);

  const float4 gv = *(const float4*)(g + i0);
  const float4 bv = *(const float4*)(be + i0);
  const float o0 = (v[0] - mu) * rstd * gv.x + bv.x;
  const float o1 = (v[1] - mu) * rstd * gv.y + bv.y;
  const float o2 = (v[2] - mu) * rstd * gv.z + bv.z;
  const float o3 = (v[3] - mu) * rstd * gv.w + bv.w;
  if constexpr (OUT_F32) {
    float4 ov; ov.x = o0; ov.y = o1; ov.z = o2; ov.w = o3;
    *(float4*)((float*)outv + base + i0) = ov;
  } else {
    u16x4 ob = { f2bf(o0), f2bf(o1), f2bf(o2), f2bf(o3) };
    *(u16x4*)((ushort_t*)outv + base + i0) = ob;
  }
}

__global__ __launch_bounds__(256) void cast_f32_bf16(const float* __restrict__ src,
                                                     ushort_t* __restrict__ dst, int n4)
{
  const int i = blockIdx.x * 256 + threadIdx.x;
  if (i >= n4) return;
  const float4 v = *(const float4*)(src + ((long)i << 2));
  u16x4 o = { f2bf(v.x), f2bf(v.y), f2bf(v.z), f2bf(v.w) };
  *(u16x4*)(dst + ((long)i << 2)) = o;
}

// ---------------------------------------------------------------------------
// Memory plan (peak ~106 MiB of ws; d_out doubles as scratch):
//   d_out:  [q 32MiB | k 32MiB]  -> (after scores) attb in [0..32MiB) -> final fp32 out
//   ws:     R0 = 64MiB multi-use: [xb 32 | v 32] -> S(64) -> [hb 32 | ff1 32]
//           R1 = 32MiB: vt -> ff2
//           R2 = 10MiB: bf16 weights wq wk wv wf1 wf2
// Every region is fully written before read within the call; lifetimes audited:
//   xb dead after QKV gemms; v dead after transpose; S (overwrites xb+v) dead
//   after PV; q/k dead after scores; vt dead after PV; attb dead after LN1.
// ---------------------------------------------------------------------------
extern "C" void kernel_launch(void* const* d_in, const int* in_sizes, int n_in,
                              void* d_out, int out_size, void* d_ws, size_t ws_size,
                              hipStream_t stream) {
  const int T = 2048, D = 1024;
  const long TD = (long)T * D;        // 2M  (per-batch q/k/v elements)
  const long ND = 8 * TD;             // 16M (B*T*D)
  const float* x    = (const float*)d_in[0];
  const float* sit  = (const float*)d_in[1];
  const float* Wq   = (const float*)d_in[2];
  const float* Wk   = (const float*)d_in[3];
  const float* Wv   = (const float*)d_in[4];
  const float* ln1g = (const float*)d_in[5];
  const float* ln1b = (const float*)d_in[6];
  const float* Wf1  = (const float*)d_in[7];
  const float* bf1  = (const float*)d_in[8];
  const float* Wf2  = (const float*)d_in[9];
  const float* bf2  = (const float*)d_in[10];
  const float* ln2g = (const float*)d_in[11];
  const float* ln2b = (const float*)d_in[12];

  ushort_t* W16 = (ushort_t*)d_ws;
  // region 0 (64 MiB = 32M bf16 elements), multi-use
  ushort_t* xb  = W16;                 // 16M elems
  ushort_t* vb  = W16 + ND;            // 16M elems
  ushort_t* S   = W16;                 // 32M elems (scores/P)
  ushort_t* hb  = W16;                 // 16M elems
  ushort_t* ff1 = W16 + ND;            // 16M elems
  // region 1 (32 MiB)
  ushort_t* vt  = W16 + 2 * ND;        // 16M elems
  ushort_t* ff2 = vt;
  // region 2 (10 MiB): bf16 weights
  ushort_t* wq  = W16 + 3 * ND;
  ushort_t* wk  = wq + (long)D * D;
  ushort_t* wv  = wk + (long)D * D;
  ushort_t* wf1 = wv + (long)D * D;
  ushort_t* wf2 = wf1 + (long)D * D;
  // q/k live in d_out (bf16) until scores are done
  ushort_t* qb = (ushort_t*)d_out;     // 16M elems
  ushort_t* kb = qb + ND;              // 16M elems
  ushort_t* attb = (ushort_t*)d_out;   // reuse after q/k dead

  // casts to bf16
  cast_f32_bf16<<<16384, 256, 0, stream>>>(x, xb, (int)(ND / 4));
  cast_f32_bf16<<<1024, 256, 0, stream>>>(Wq, wq, D * D / 4);
  cast_f32_bf16<<<1024, 256, 0, stream>>>(Wk, wk, D * D / 4);
  cast_f32_bf16<<<1024, 256, 0, stream>>>(Wv, wv, D * D / 4);
  cast_f32_bf16<<<1024, 256, 0, stream>>>(Wf1, wf1, D * D / 4);
  cast_f32_bf16<<<1024, 256, 0, stream>>>(Wf2, wf2, D * D / 4);

  // q/k/v projections: [16384,1024] @ [1024,1024]^T
  gemm128<0, false, false><<<dim3(8, 128, 1), 256, 0, stream>>>(
      xb, 1024, 0, wq, 1024, 0, qb, 1024, 0, nullptr, 1.f, 1024);
  gemm128<0, false, false><<<dim3(8, 128, 1), 256, 0, stream>>>(
      xb, 1024, 0, wk, 1024, 0, kb, 1024, 0, nullptr, 1.f, 1024);
  gemm128<0, false, false><<<dim3(8, 128, 1), 256, 0, stream>>>(
      xb, 1024, 0, wv, 1024, 0, vb, 1024, 0, nullptr, 1.f, 1024);

  // V^T per batch: [2048,1024] -> [1024,2048]
  transpose_bf16<<<dim3(16, 32, 8), 256, 0, stream>>>(
      vb, 1024, TD, vt, 2048, TD);

  // scores: S = Q K^T / 32, causal tile skip (overwrites xb+vb — both dead)
  gemm128<0, true, false><<<dim3(16, 16, 8), 256, 0, stream>>>(
      qb, 1024, TD, kb, 1024, TD, S, 2048, (long)T * T, nullptr, 0.03125f, 1024);

  // softmax + SIT mask, in-place P
  softmax_sit<<<16384, 256, 0, stream>>>(S, sit);

  // att = P @ V (NT via V^T), causal K limit; writes d_out[0..32MiB) (q/k dead)
  gemm128<0, false, true><<<dim3(8, 16, 8), 256, 0, stream>>>(
      S, 2048, (long)T * T, vt, 2048, TD, attb, 1024, TD, nullptr, 1.f, 2048);

  // h = LN(att + x)  (S dead after PV -> hb overwrites it)
  resid_ln<true, false><<<16384, 256, 0, stream>>>(attb, x, ln1g, ln1b, hb);

  // ff1 = relu(h @ Wf1^T + bf1)
  gemm128<2, false, false><<<dim3(8, 128, 1), 256, 0, stream>>>(
      hb, 1024, 0, wf1, 1024, 0, ff1, 1024, 0, bf1, 1.f, 1024);

  // ff2 = ff1 @ Wf2^T + bf2  (vt dead -> ff2 overwrites it)
  gemm128<1, false, false><<<dim3(8, 128, 1), 256, 0, stream>>>(
      ff1, 1024, 0, wf2, 1024, 0, ff2, 1024, 0, bf2, 1.f, 1024);

  // out = LN(ff2 + h) in fp32 (reads only ws; overwrites all of d_out)
  resid_ln<false, true><<<16384, 256, 0, stream>>>(ff2, hb, ln2g, ln2b, (float*)d_out);
}

// Round 3
// 429.142 us; speedup vs baseline: 1.4320x; 1.4320x over previous
//
#include <hip/hip_runtime.h>

typedef unsigned short ushort_t;
typedef __attribute__((ext_vector_type(8))) __bf16 bf16x8;
typedef __attribute__((ext_vector_type(4))) float f32x4;
typedef __attribute__((ext_vector_type(4))) int i32x4;
typedef __attribute__((ext_vector_type(4))) unsigned short u16x4;

__device__ __forceinline__ float bf2f(ushort_t u) {
  union { unsigned u32; float f; } c; c.u32 = ((unsigned)u) << 16; return c.f;
}
__device__ __forceinline__ ushort_t f2bf(float f) {
  union { float f; unsigned u32; } c; c.f = f;
  unsigned u = c.u32;
  u += 0x7fffu + ((u >> 16) & 1u);
  return (ushort_t)(u >> 16);
}

__device__ __forceinline__ void gload_lds16(const void* g, void* l) {
  __builtin_amdgcn_global_load_lds(
      (const __attribute__((address_space(1))) void*)g,
      (__attribute__((address_space(3))) void*)l,
      16, 0, 0);
}

// Stage one 128x64 bf16 half-tile: linear LDS dest, inverse-swizzled global src
// (chunk_src = chunk ^ (row&7)); 2 x global_load_lds(16B) per thread.
__device__ __forceinline__ void stage_half(const char* gbase, long row0, int ldbytes,
                                           int kbyte, char* lds_half, int tid)
{
  const int rl = tid >> 3;                         // 0..63
  const int cs = ((tid & 7) ^ (rl & 7)) << 4;      // pre-swizzled 16B chunk
  const char* g0 = gbase + (row0 + rl) * (long)ldbytes + kbyte + cs;
  char* l0 = lds_half + ((tid >> 6) << 10);        // wave-uniform base (+lane*16 HW)
  gload_lds16(g0, l0);
  gload_lds16(g0 + (long)ldbytes * 64, l0 + 8192);
}

#define FENCE() asm volatile("" ::: "memory")
#define BARX() do { FENCE(); __builtin_amdgcn_sched_barrier(0); \
  __builtin_amdgcn_s_barrier(); __builtin_amdgcn_sched_barrier(0); FENCE(); } while (0)
#define VMW4() do { FENCE(); asm volatile("s_waitcnt vmcnt(4)" ::: "memory"); FENCE(); } while (0)
#define PR1() __builtin_amdgcn_s_setprio(1)
#define PR0() __builtin_amdgcn_s_setprio(0)

// ds-read macros: swizzled chunk offsets ch0/ch1 precomputed per lane
#define READ_A(dst, Abase, mb) \
  _Pragma("unroll") for (int m_ = 0; m_ < 4; ++m_) { \
    const char* p_ = (Abase) + ((wr << 7) + (mb) + m_ * 16 + fr) * 128; \
    dst[m_][0] = *(const bf16x8*)(p_ + ch0); \
    dst[m_][1] = *(const bf16x8*)(p_ + ch1); }

#define READ_B(dst, Bbase, jb) \
  _Pragma("unroll") for (int n_ = 0; n_ < 2; ++n_) { \
    const char* p_ = (Bbase) + ((wc << 6) + (jb) + n_ * 16 + fr) * 128; \
    dst[n_][0] = *(const bf16x8*)(p_ + ch0); \
    dst[n_][1] = *(const bf16x8*)(p_ + ch1); }

#define MFMA_Q(ib, jb, aarr, barr) \
  _Pragma("unroll") for (int m_ = 0; m_ < 4; ++m_) \
  _Pragma("unroll") for (int n_ = 0; n_ < 2; ++n_) \
  _Pragma("unroll") for (int s_ = 0; s_ < 2; ++s_) \
    acc[(ib) + m_][(jb) + n_] = __builtin_amdgcn_mfma_f32_16x16x32_bf16( \
        aarr[m_][s_], barr[n_][s_], acc[(ib) + m_][(jb) + n_], 0, 0, 0);

#define STAGE_A(t, h, db) stage_half(gA, m0 + (h) * 128, ldab, (t) << 7, \
    (char*)lds + (db) * 32768 + (h) * 16384, tid)
#define STAGE_B(t, h, db) stage_half(gB, n0 + (h) * 128, ldbb, (t) << 7, \
    (char*)lds + 65536 + (db) * 32768 + (h) * 16384, tid)

// ---------------------------------------------------------------------------
// 256x256 bf16 NT GEMM, 8-phase schedule (T2 swizzle + T3/T4 counted vmcnt +
// T5 setprio). BK=64, 8 waves (2M x 4N), per-wave out 128x64, LDS 128 KiB.
// EPI: 0 none, 1 +bias, 2 +bias+relu. TRI: triangular grid (causal scores).
// CKLIM: K limited to (by+1)*256 (causal PV).
// ---------------------------------------------------------------------------
template<int EPI, bool TRI, bool CKLIM>
__global__ __launch_bounds__(512, 2) void gemm256(
    const ushort_t* __restrict__ A, int lda, long bsA,
    const ushort_t* __restrict__ B, int ldb, long bsB,
    ushort_t* __restrict__ C, int ldc, long bsC,
    const float* __restrict__ bias, float scale, int K)
{
  __shared__ __attribute__((aligned(16))) ushort_t lds[65536];  // 128 KiB

  int bx, by;
  if (TRI) {
    int bid = blockIdx.x; by = 0;
    while ((by + 1) * (by + 2) / 2 <= bid) ++by;
    bx = bid - by * (by + 1) / 2;
  } else { bx = blockIdx.x; by = blockIdx.y; }
  const int bz = blockIdx.z;
  const int NT = CKLIM ? ((by + 1) << 2) : (K >> 6);
  const int NIT = NT >> 1, NTm1 = NT - 1;

  const int tid = threadIdx.x;
  const int lane = tid & 63, fr = lane & 15, g = lane >> 4, lm = lane & 7;
  const int wv = tid >> 6, wr = wv >> 2, wc = wv & 3;
  const long m0 = (long)by << 8, n0 = (long)bx << 8;

  const char* gA = (const char*)(A + bz * bsA);
  const char* gB = (const char*)(B + bz * bsB);
  const int ldab = lda << 1, ldbb = ldb << 1;

  const int ch0 = (g ^ lm) << 4;          // swizzled 16B-chunk offset, kstep 0
  const int ch1 = ((4 | g) ^ lm) << 4;    // kstep 1

  const char* A0 = (const char*)lds;
  const char* A1 = (const char*)lds + 32768;
  const char* B0 = (const char*)lds + 65536;
  const char* B1 = (const char*)lds + 98304;

  f32x4 acc[8][4] = {};
  bf16x8 aF[4][2], aG[4][2], bX[2][2];

  // prologue: T0 (A0,A1,B0,B1) + T1 (A0,A1); vmcnt(4) -> T0 landed
  STAGE_A(0, 0, 0); STAGE_A(0, 1, 0); STAGE_B(0, 0, 0); STAGE_B(0, 1, 0);
  STAGE_A(1, 0, 1); STAGE_A(1, 1, 1);
  VMW4(); BARX();

  for (int i = 0; i < NIT; ++i) {
    const int t1 = 2 * i + 1;
    const int t2 = (2 * i + 2 < NTm1) ? 2 * i + 2 : NTm1;   // clamped (tail garbage ok)
    const int t3 = (2 * i + 3 < NTm1) ? 2 * i + 3 : NTm1;

    // ph1: quad (mlo,nlo) of buf0-tile
    READ_A(aF, A0, 0); READ_B(bX, B0, 0);
    STAGE_B(t1, 0, 1);
    BARX(); PR1(); MFMA_Q(0, 0, aF, bX); PR0(); BARX();
    // ph2: (mhi,nlo)
    READ_A(aG, A0, 64);
    STAGE_B(t1, 1, 1);
    BARX(); PR1(); MFMA_Q(4, 0, aG, bX); PR0(); BARX();
    // ph3: (mhi,nhi)
    READ_B(bX, B0, 32);
    STAGE_A(t2, 0, 0);
    BARX(); PR1(); MFMA_Q(4, 2, aG, bX); PR0(); BARX();
    // ph4: (mlo,nhi)
    STAGE_A(t2, 1, 0);
    BARX(); PR1(); MFMA_Q(0, 2, aF, bX); PR0(); VMW4(); BARX();
    // ph5: quad (mlo,nlo) of buf1-tile
    READ_A(aF, A1, 0); READ_B(bX, B1, 0);
    STAGE_B(t2, 0, 0);
    BARX(); PR1(); MFMA_Q(0, 0, aF, bX); PR0(); BARX();
    // ph6: (mhi,nlo)
    READ_A(aG, A1, 64);
    STAGE_B(t2, 1, 0);
    BARX(); PR1(); MFMA_Q(4, 0, aG, bX); PR0(); BARX();
    // ph7: (mhi,nhi)
    READ_B(bX, B1, 32);
    STAGE_A(t3, 0, 1);
    BARX(); PR1(); MFMA_Q(4, 2, aG, bX); PR0(); BARX();
    // ph8: (mlo,nhi)
    STAGE_A(t3, 1, 1);
    BARX(); PR1(); MFMA_Q(0, 2, aF, bX); PR0(); VMW4(); BARX();
  }

  ushort_t* Cb = C + bz * bsC;
  const int cm = g << 2, cn = fr;
#pragma unroll
  for (int i2 = 0; i2 < 8; ++i2)
#pragma unroll
    for (int j2 = 0; j2 < 4; ++j2) {
      const long gm = m0 + (wr << 7) + i2 * 16 + cm;
      const long gn = n0 + (wc << 6) + j2 * 16 + cn;
      float bv = 0.f;
      if constexpr (EPI >= 1) bv = bias[gn];
#pragma unroll
      for (int r = 0; r < 4; ++r) {
        float v = acc[i2][j2][r] * scale + bv;
        if constexpr (EPI == 2) v = fmaxf(v, 0.f);
        Cb[(gm + r) * ldc + gn] = f2bf(v);
      }
    }
}

// ---------------------------------------------------------------------------
// 64x64 bf16 transpose: Vt[d][s] = V[s][d]
// ---------------------------------------------------------------------------
__global__ __launch_bounds__(256) void transpose_bf16(
    const ushort_t* __restrict__ V, int ldv, long bsV,
    ushort_t* __restrict__ Vt, int ldt, long bsT)
{
  __shared__ __attribute__((aligned(16))) ushort_t tile[64][72];
  const int bz = blockIdx.z;
  const ushort_t* Vb = V + bz * bsV;
  ushort_t* Tb = Vt + bz * bsT;
  const long s0 = (long)blockIdx.y << 6;
  const long d0 = (long)blockIdx.x << 6;
  const int tid = threadIdx.x;
  const int r = tid >> 3, c = tid & 7;
#pragma unroll
  for (int h = 0; h < 2; ++h) {
    const int rr = r + h * 32;
    i32x4 v = *(const i32x4*)(Vb + (s0 + rr) * ldv + d0 + c * 8);
    *(i32x4*)&tile[rr][c * 8] = v;
  }
  __syncthreads();
#pragma unroll
  for (int h = 0; h < 2; ++h) {
    const int dr = r + h * 32;
    union { ushort_t u[8]; i32x4 v; } t;
#pragma unroll
    for (int j = 0; j < 8; ++j) t.u[j] = tile[c * 8 + j][dr];
    *(i32x4*)(Tb + (d0 + dr) * ldt + s0 + c * 8) = t.v;
  }
}

// ---------------------------------------------------------------------------
// Row softmax over s<=t (denominator over ALL s<=t; SIT applied AFTER),
// writes P bf16 in place, zero-fills to next 256 boundary (PV uses 256 tiles).
// ---------------------------------------------------------------------------
__global__ __launch_bounds__(256) void softmax_sit(ushort_t* __restrict__ S,
                                                   const float* __restrict__ sit)
{
  __shared__ float buf[2048];
  __shared__ float red[4];
  const long row = blockIdx.x;
  const int b = (int)(row >> 11);
  const int t = (int)(row & 2047);
  ushort_t* Srow = S + (row << 11);
  const int tid = threadIdx.x;
  const int n = t + 1;

  float mloc = -3.0e38f;
  for (int i = tid; i < n; i += 256) {
    float v = bf2f(Srow[i]);
    buf[i] = v;
    mloc = fmaxf(mloc, v);
  }
#pragma unroll
  for (int o = 32; o > 0; o >>= 1) mloc = fmaxf(mloc, __shfl_down(mloc, o, 64));
  if ((tid & 63) == 0) red[tid >> 6] = mloc;
  __syncthreads();
  const float m = fmaxf(fmaxf(red[0], red[1]), fmaxf(red[2], red[3]));
  __syncthreads();

  float sloc = 0.f;
  for (int i = tid; i < n; i += 256) sloc += __expf(buf[i] - m);
#pragma unroll
  for (int o = 32; o > 0; o >>= 1) sloc += __shfl_down(sloc, o, 64);
  if ((tid & 63) == 0) red[tid >> 6] = sloc;
  __syncthreads();
  const float l = red[0] + red[1] + red[2] + red[3];

  float inv = 1.f / l;
  if (sit[row] == 0.f) inv = 0.f;
  const float* sitb = sit + ((long)b << 11);
  const int rup = ((t >> 8) + 1) << 8;
  for (int i = tid; i < rup; i += 256) {
    float p = 0.f;
    if (i < n && sitb[i] != 0.f) p = __expf(buf[i] - m) * inv;
    Srow[i] = f2bf(p);
  }
}

// ---------------------------------------------------------------------------
// out = LN(xin + res) * g + b ; D = 1024, one block per row
// ---------------------------------------------------------------------------
template<bool RES_F32, bool OUT_F32>
__global__ __launch_bounds__(256) void resid_ln(
    const ushort_t* __restrict__ xin, const void* __restrict__ resv,
    const float* __restrict__ g, const float* __restrict__ be, void* __restrict__ outv)
{
  __shared__ float red[4];
  const long base = (long)blockIdx.x << 10;
  const int tid = threadIdx.x;
  const int i0 = tid << 2;

  const u16x4 xa = *(const u16x4*)(xin + base + i0);
  float v[4];
  if constexpr (RES_F32) {
    const float4 rv = *(const float4*)((const float*)resv + base + i0);
    v[0] = bf2f(xa.x) + rv.x; v[1] = bf2f(xa.y) + rv.y;
    v[2] = bf2f(xa.z) + rv.z; v[3] = bf2f(xa.w) + rv.w;
  } else {
    const u16x4 rb = *(const u16x4*)((const ushort_t*)resv + base + i0);
    v[0] = bf2f(xa.x) + bf2f(rb.x); v[1] = bf2f(xa.y) + bf2f(rb.y);
    v[2] = bf2f(xa.z) + bf2f(rb.z); v[3] = bf2f(xa.w) + bf2f(rb.w);
  }
  float s = v[0] + v[1] + v[2] + v[3];
#pragma unroll
  for (int o = 32; o > 0; o >>= 1) s += __shfl_down(s, o, 64);
  if ((tid & 63) == 0) red[tid >> 6] = s;
  __syncthreads();
  const float mu = (red[0] + red[1] + red[2] + red[3]) * (1.f / 1024.f);
  __syncthreads();
  float s2 = 0.f;
#pragma unroll
  for (int j = 0; j < 4; ++j) { const float d = v[j] - mu; s2 += d * d; }
#pragma unroll
  for (int o = 32; o > 0; o >>= 1) s2 += __shfl_down(s2, o, 64);
  if ((tid & 63) == 0) red[tid >> 6] = s2;
  __syncthreads();
  const float rstd = rsqrtf((red[0] + red[1] + red[2] + red[3]) * (1.f / 1024.f) + 1e-5f);

  const float4 gv = *(const float4*)(g + i0);
  const float4 bv = *(const float4*)(be + i0);
  const float o0 = (v[0] - mu) * rstd * gv.x + bv.x;
  const float o1 = (v[1] - mu) * rstd * gv.y + bv.y;
  const float o2 = (v[2] - mu) * rstd * gv.z + bv.z;
  const float o3 = (v[3] - mu) * rstd * gv.w + bv.w;
  if constexpr (OUT_F32) {
    float4 ov; ov.x = o0; ov.y = o1; ov.z = o2; ov.w = o3;
    *(float4*)((float*)outv + base + i0) = ov;
  } else {
    u16x4 ob = { f2bf(o0), f2bf(o1), f2bf(o2), f2bf(o3) };
    *(u16x4*)((ushort_t*)outv + base + i0) = ob;
  }
}

__global__ __launch_bounds__(256) void cast_f32_bf16(const float* __restrict__ src,
                                                     ushort_t* __restrict__ dst, int n4)
{
  const int i = blockIdx.x * 256 + threadIdx.x;
  if (i >= n4) return;
  const float4 v = *(const float4*)(src + ((long)i << 2));
  u16x4 o = { f2bf(v.x), f2bf(v.y), f2bf(v.z), f2bf(v.w) };
  *(u16x4*)(dst + ((long)i << 2)) = o;
}

// ---------------------------------------------------------------------------
// Memory plan (as round 2, verified green):
//   d_out: [q|k] bf16 -> attb -> final fp32
//   ws R0 (64MiB): [xb|vb] -> S -> [hb|ff1];  R1 (32MiB): vt -> ff2;  R2: weights
// ---------------------------------------------------------------------------
extern "C" void kernel_launch(void* const* d_in, const int* in_sizes, int n_in,
                              void* d_out, int out_size, void* d_ws, size_t ws_size,
                              hipStream_t stream) {
  const int T = 2048, D = 1024;
  const long TD = (long)T * D;
  const long ND = 8 * TD;
  const float* x    = (const float*)d_in[0];
  const float* sit  = (const float*)d_in[1];
  const float* Wq   = (const float*)d_in[2];
  const float* Wk   = (const float*)d_in[3];
  const float* Wv   = (const float*)d_in[4];
  const float* ln1g = (const float*)d_in[5];
  const float* ln1b = (const float*)d_in[6];
  const float* Wf1  = (const float*)d_in[7];
  const float* bf1  = (const float*)d_in[8];
  const float* Wf2  = (const float*)d_in[9];
  const float* bf2  = (const float*)d_in[10];
  const float* ln2g = (const float*)d_in[11];
  const float* ln2b = (const float*)d_in[12];

  ushort_t* W16 = (ushort_t*)d_ws;
  ushort_t* xb  = W16;
  ushort_t* vb  = W16 + ND;
  ushort_t* S   = W16;
  ushort_t* hb  = W16;
  ushort_t* ff1 = W16 + ND;
  ushort_t* vt  = W16 + 2 * ND;
  ushort_t* ff2 = vt;
  ushort_t* wq  = W16 + 3 * ND;
  ushort_t* wk  = wq + (long)D * D;
  ushort_t* wv  = wk + (long)D * D;
  ushort_t* wf1 = wv + (long)D * D;
  ushort_t* wf2 = wf1 + (long)D * D;
  ushort_t* qb = (ushort_t*)d_out;
  ushort_t* kb = qb + ND;
  ushort_t* attb = (ushort_t*)d_out;

  cast_f32_bf16<<<16384, 256, 0, stream>>>(x, xb, (int)(ND / 4));
  cast_f32_bf16<<<1024, 256, 0, stream>>>(Wq, wq, D * D / 4);
  cast_f32_bf16<<<1024, 256, 0, stream>>>(Wk, wk, D * D / 4);
  cast_f32_bf16<<<1024, 256, 0, stream>>>(Wv, wv, D * D / 4);
  cast_f32_bf16<<<1024, 256, 0, stream>>>(Wf1, wf1, D * D / 4);
  cast_f32_bf16<<<1024, 256, 0, stream>>>(Wf2, wf2, D * D / 4);

  // q/k/v projections: [16384,1024] @ [1024,1024]^T, 256 blocks each (1/CU)
  gemm256<0, false, false><<<dim3(4, 64, 1), 512, 0, stream>>>(
      xb, 1024, 0, wq, 1024, 0, qb, 1024, 0, nullptr, 1.f, 1024);
  gemm256<0, false, false><<<dim3(4, 64, 1), 512, 0, stream>>>(
      xb, 1024, 0, wk, 1024, 0, kb, 1024, 0, nullptr, 1.f, 1024);
  gemm256<0, false, false><<<dim3(4, 64, 1), 512, 0, stream>>>(
      xb, 1024, 0, wv, 1024, 0, vb, 1024, 0, nullptr, 1.f, 1024);

  transpose_bf16<<<dim3(16, 32, 8), 256, 0, stream>>>(
      vb, 1024, TD, vt, 2048, TD);

  // scores: S = Q K^T / 32, triangular 256-tile grid (36 tiles/batch)
  gemm256<0, true, false><<<dim3(36, 1, 8), 512, 0, stream>>>(
      qb, 1024, TD, kb, 1024, TD, S, 2048, (long)T * T, nullptr, 0.03125f, 1024);

  softmax_sit<<<16384, 256, 0, stream>>>(S, sit);

  // att = P @ V (NT via V^T), causal K-limit per 256-row tile
  gemm256<0, false, true><<<dim3(4, 8, 8), 512, 0, stream>>>(
      S, 2048, (long)T * T, vt, 2048, TD, attb, 1024, TD, nullptr, 1.f, 2048);

  resid_ln<true, false><<<16384, 256, 0, stream>>>(attb, x, ln1g, ln1b, hb);

  gemm256<2, false, false><<<dim3(4, 64, 1), 512, 0, stream>>>(
      hb, 1024, 0, wf1, 1024, 0, ff1, 1024, 0, bf1, 1.f, 1024);
  gemm256<1, false, false><<<dim3(4, 64, 1), 512, 0, stream>>>(
      ff1, 1024, 0, wf2, 1024, 0, ff2, 1024, 0, bf2, 1.f, 1024);

  resid_ln<false, true><<<16384, 256, 0, stream>>>(ff2, hb, ln2g, ln2b, (float*)d_out);
}

// Round 4
// 401.544 us; speedup vs baseline: 1.5304x; 1.0687x over previous
//
#include <hip/hip_runtime.h>

typedef unsigned short ushort_t;
typedef __attribute__((ext_vector_type(8))) __bf16 bf16x8;
typedef __attribute__((ext_vector_type(4))) float f32x4;
typedef __attribute__((ext_vector_type(4))) int i32x4;
typedef __attribute__((ext_vector_type(4))) unsigned short u16x4;
typedef __attribute__((ext_vector_type(8))) unsigned short u16x8;

__device__ __forceinline__ float bf2f(ushort_t u) {
  union { unsigned u32; float f; } c; c.u32 = ((unsigned)u) << 16; return c.f;
}
__device__ __forceinline__ ushort_t f2bf(float f) {
  union { float f; unsigned u32; } c; c.f = f;
  unsigned u = c.u32;
  u += 0x7fffu + ((u >> 16) & 1u);
  return (ushort_t)(u >> 16);
}

__device__ __forceinline__ void gload_lds16(const void* g, void* l) {
  __builtin_amdgcn_global_load_lds(
      (const __attribute__((address_space(1))) void*)g,
      (__attribute__((address_space(3))) void*)l,
      16, 0, 0);
}

// Stage one 128x64 bf16 half-tile: linear LDS dest, inverse-swizzled global src
__device__ __forceinline__ void stage_half(const char* gbase, long row0, int ldbytes,
                                           int kbyte, char* lds_half, int tid)
{
  const int rl = tid >> 3;
  const int cs = ((tid & 7) ^ (rl & 7)) << 4;
  const char* g0 = gbase + (row0 + rl) * (long)ldbytes + kbyte + cs;
  char* l0 = lds_half + ((tid >> 6) << 10);
  gload_lds16(g0, l0);
  gload_lds16(g0 + (long)ldbytes * 64, l0 + 8192);
}

#define BAR() __builtin_amdgcn_s_barrier()
#define VMW4() asm volatile("s_waitcnt vmcnt(4)" ::: "memory")
#define VMW2() asm volatile("s_waitcnt vmcnt(2)" ::: "memory")
#define VMW6() asm volatile("s_waitcnt vmcnt(6)" ::: "memory")
#define PR1() __builtin_amdgcn_s_setprio(1)
#define PR0() __builtin_amdgcn_s_setprio(0)

// shared ds-read / mfma macros (use local names: wr, wc, fr, ch0, ch1)
#define READ_A(dst, Abase, mb) \
  _Pragma("unroll") for (int m_ = 0; m_ < 4; ++m_) { \
    const char* p_ = (Abase) + ((wr << 7) + (mb) + m_ * 16 + fr) * 128; \
    dst[m_][0] = *(const bf16x8*)(p_ + ch0); \
    dst[m_][1] = *(const bf16x8*)(p_ + ch1); }

// ===========================================================================
// gemm256: 256x256 bf16 NT GEMM, 8-phase (T2 swizzle + T3/T4 + T5).
// BK=64, 8 waves (2Mx4N), per-wave 128x64. Used for QKV/FFN (uniform K).
// SWZ: same-by blocks -> same XCD (grid must be 4x64).
// ===========================================================================
#define READ_B4(dst, Bbase, jb) \
  _Pragma("unroll") for (int n_ = 0; n_ < 2; ++n_) { \
    const char* p_ = (Bbase) + ((wc << 6) + (jb) + n_ * 16 + fr) * 128; \
    dst[n_][0] = *(const bf16x8*)(p_ + ch0); \
    dst[n_][1] = *(const bf16x8*)(p_ + ch1); }

#define MFMA_Q(ib, jb, aarr, barr) \
  _Pragma("unroll") for (int m_ = 0; m_ < 4; ++m_) \
  _Pragma("unroll") for (int n_ = 0; n_ < 2; ++n_) \
  _Pragma("unroll") for (int s_ = 0; s_ < 2; ++s_) \
    acc[(ib) + m_][(jb) + n_] = __builtin_amdgcn_mfma_f32_16x16x32_bf16( \
        aarr[m_][s_], barr[n_][s_], acc[(ib) + m_][(jb) + n_], 0, 0, 0);

#define STAGE_A(t, h, db) stage_half(gA, m0 + (h) * 128, ldab, (t) << 7, \
    (char*)lds + (db) * 32768 + (h) * 16384, tid)
#define STAGE_B(t, h, db) stage_half(gB, n0 + (h) * 128, ldbb, (t) << 7, \
    (char*)lds + 65536 + (db) * 32768 + (h) * 16384, tid)

template<int EPI, bool SWZ>
__global__ __launch_bounds__(512, 1) void gemm256(
    const ushort_t* __restrict__ A, int lda,
    const ushort_t* __restrict__ B, int ldb,
    ushort_t* __restrict__ C, int ldc,
    const float* __restrict__ bias, float scale, int K)
{
  __shared__ __attribute__((aligned(16))) ushort_t lds[65536];

  int bx, by;
  if (SWZ) {
    const int flat = blockIdx.y * 4 + blockIdx.x;       // grid is 4x64
    by = ((flat >> 5) << 3) | (flat & 7);               // same-by -> same XCD
    bx = (flat >> 3) & 3;
  } else { bx = blockIdx.x; by = blockIdx.y; }

  const int NT = K >> 6;
  const int NIT = NT >> 1, NTm1 = NT - 1;

  const int tid = threadIdx.x;
  const int lane = tid & 63, fr = lane & 15, g = lane >> 4, lm = lane & 7;
  const int wv = tid >> 6, wr = wv >> 2, wc = wv & 3;
  const long m0 = (long)by << 8, n0 = (long)bx << 8;

  const char* gA = (const char*)A;
  const char* gB = (const char*)B;
  const int ldab = lda << 1, ldbb = ldb << 1;

  const int ch0 = (g ^ lm) << 4;
  const int ch1 = ((4 | g) ^ lm) << 4;

  const char* A0 = (const char*)lds;
  const char* A1 = (const char*)lds + 32768;
  const char* B0 = (const char*)lds + 65536;
  const char* B1 = (const char*)lds + 98304;

  f32x4 acc[8][4] = {};
  bf16x8 aF[4][2], aG[4][2], bX[2][2];

  STAGE_A(0, 0, 0); STAGE_A(0, 1, 0); STAGE_B(0, 0, 0); STAGE_B(0, 1, 0);
  STAGE_A(1, 0, 1); STAGE_A(1, 1, 1);
  VMW4(); BAR();

  for (int i = 0; i < NIT; ++i) {
    const int t1 = 2 * i + 1;
    const int t2 = (2 * i + 2 < NTm1) ? 2 * i + 2 : NTm1;
    const int t3 = (2 * i + 3 < NTm1) ? 2 * i + 3 : NTm1;

    READ_A(aF, A0, 0); READ_B4(bX, B0, 0);
    STAGE_B(t1, 0, 1);
    BAR(); PR1(); MFMA_Q(0, 0, aF, bX); PR0(); BAR();

    READ_A(aG, A0, 64);
    STAGE_B(t1, 1, 1);
    BAR(); PR1(); MFMA_Q(4, 0, aG, bX); PR0(); BAR();

    READ_B4(bX, B0, 32);
    STAGE_A(t2, 0, 0);
    BAR(); PR1(); MFMA_Q(4, 2, aG, bX); PR0(); BAR();

    STAGE_A(t2, 1, 0);
    BAR(); PR1(); MFMA_Q(0, 2, aF, bX); PR0(); VMW4(); BAR();

    READ_A(aF, A1, 0); READ_B4(bX, B1, 0);
    STAGE_B(t2, 0, 0);
    BAR(); PR1(); MFMA_Q(0, 0, aF, bX); PR0(); BAR();

    READ_A(aG, A1, 64);
    STAGE_B(t2, 1, 0);
    BAR(); PR1(); MFMA_Q(4, 0, aG, bX); PR0(); BAR();

    READ_B4(bX, B1, 32);
    STAGE_A(t3, 0, 1);
    BAR(); PR1(); MFMA_Q(4, 2, aG, bX); PR0(); BAR();

    STAGE_A(t3, 1, 1);
    BAR(); PR1(); MFMA_Q(0, 2, aF, bX); PR0(); VMW4(); BAR();
  }

  const int cm = g << 2, cn = fr;
#pragma unroll
  for (int i2 = 0; i2 < 8; ++i2)
#pragma unroll
    for (int j2 = 0; j2 < 4; ++j2) {
      const long gm = m0 + (wr << 7) + i2 * 16 + cm;
      const long gn = n0 + (wc << 6) + j2 * 16 + cn;
      float bv = 0.f;
      if constexpr (EPI >= 1) bv = bias[gn];
#pragma unroll
      for (int r = 0; r < 4; ++r) {
        float v = acc[i2][j2][r] * scale + bv;
        if constexpr (EPI == 2) v = fmaxf(v, 0.f);
        C[(gm + r) * ldc + gn] = f2bf(v);
      }
    }
}

// ===========================================================================
// gemmA: 256x128 bf16 NT GEMM, 4-phase per 2 K-tiles (same 16-MFMA phase
// density), VMW(2) cadence. LDS 96 KiB. Per-wave out 128x32.
// MAP: 1 = triangular 128-col scores grid (72 tiles/batch, grid=576),
//      2 = heavy-first PV grid (512 blocks, by = 7-(bid>>6)), K=(by+1)*256.
// ===========================================================================
#define READ_B2(dst, Bbase) \
  _Pragma("unroll") for (int n_ = 0; n_ < 2; ++n_) { \
    const char* p_ = (Bbase) + ((wc << 5) + n_ * 16 + fr) * 128; \
    dst[n_][0] = *(const bf16x8*)(p_ + ch0); \
    dst[n_][1] = *(const bf16x8*)(p_ + ch1); }

#define MFMA_H(ib, aarr) \
  _Pragma("unroll") for (int m_ = 0; m_ < 4; ++m_) \
  _Pragma("unroll") for (int n_ = 0; n_ < 2; ++n_) \
  _Pragma("unroll") for (int s_ = 0; s_ < 2; ++s_) \
    acc[(ib) + m_][n_] = __builtin_amdgcn_mfma_f32_16x16x32_bf16( \
        aarr[m_][s_], bX[n_][s_], acc[(ib) + m_][n_], 0, 0, 0);

#define SA_(t, h, db) stage_half(gA, m0 + (h) * 128, ldab, (t) << 7, \
    (char*)lds + (db) * 32768 + (h) * 16384, tid)
#define SB_(t, db) stage_half(gB, n0, ldbb, (t) << 7, \
    (char*)lds + 65536 + (db) * 16384, tid)

template<int EPI, int MAP, bool CKLIM>
__global__ __launch_bounds__(512, 1) void gemmA(
    const ushort_t* __restrict__ A, int lda, long bsA,
    const ushort_t* __restrict__ B, int ldb, long bsB,
    ushort_t* __restrict__ C, int ldc, long bsC,
    const float* __restrict__ bias, float scale, int K)
{
  __shared__ __attribute__((aligned(16))) ushort_t lds[49152];  // 96 KiB

  int bx, by, bz;
  if (MAP == 1) {            // triangular: per batch 72 tiles (by:256r, bx:128c)
    const int bid = blockIdx.x;
    bz = bid / 72; int r = bid % 72;
    by = 0; while ((by + 1) * (by + 2) <= r) ++by;
    bx = r - by * (by + 1);
  } else if (MAP == 2) {     // heavy-first PV
    const int bid = blockIdx.x;
    by = 7 - (bid >> 6); bx = (bid >> 3) & 7; bz = bid & 7;
  } else { bx = blockIdx.x; by = blockIdx.y; bz = blockIdx.z; }

  const int NT = CKLIM ? ((by + 1) << 2) : (K >> 6);
  const int NIT = NT >> 1, NTm1 = NT - 1;

  const int tid = threadIdx.x;
  const int lane = tid & 63, fr = lane & 15, g = lane >> 4, lm = lane & 7;
  const int wv = tid >> 6, wr = wv >> 2, wc = wv & 3;
  const long m0 = (long)by << 8, n0 = (long)bx << 7;

  const char* gA = (const char*)(A + bz * bsA);
  const char* gB = (const char*)(B + bz * bsB);
  const int ldab = lda << 1, ldbb = ldb << 1;

  const int ch0 = (g ^ lm) << 4;
  const int ch1 = ((4 | g) ^ lm) << 4;

  const char* A0b = (const char*)lds;
  const char* A1b = (const char*)lds + 32768;
  const char* B0b = (const char*)lds + 65536;
  const char* B1b = (const char*)lds + 81920;

  f32x4 acc[8][2] = {};
  bf16x8 aF[4][2], aG[4][2], bX[2][2];

  // prologue: A(0) both halves -> buf0, B(0) -> buf0, B(1) -> buf1 (8 loads)
  SA_(0, 0, 0); SA_(0, 1, 0); SB_(0, 0); SB_(1, 1);
  VMW2(); BAR();

  for (int i = 0; i < NIT; ++i) {
    const int o = 2 * i + 1;
    const int t2 = (2 * i + 2 < NTm1) ? 2 * i + 2 : NTm1;
    const int t3 = (2 * i + 3 < NTm1) ? 2 * i + 3 : NTm1;

    // ph1: tile e, i=0..3
    READ_A(aF, A0b, 0); READ_B2(bX, B0b);
    SA_(o, 0, 1); SA_(o, 1, 1);
    BAR(); PR1(); MFMA_H(0, aF); PR0(); BAR();
    // ph2: tile e, i=4..7
    READ_A(aG, A0b, 64);
    SB_(t2, 0);
    BAR(); PR1(); MFMA_H(4, aG); PR0(); VMW2(); BAR();
    // ph3: tile o, i=0..3
    READ_A(aF, A1b, 0); READ_B2(bX, B1b);
    SA_(t2, 0, 0);
    BAR(); PR1(); MFMA_H(0, aF); PR0(); BAR();
    // ph4: tile o, i=4..7
    READ_A(aG, A1b, 64);
    SA_(t2, 1, 0);          // issue BEFORE SB_(t3): VMW(2) must leave only SB(t3)
    SB_(t3, 1);
    BAR(); PR1(); MFMA_H(4, aG); PR0(); VMW2(); BAR();
  }

  ushort_t* Cb = C + bz * bsC;
  const int cm = g << 2, cn = fr;
#pragma unroll
  for (int i2 = 0; i2 < 8; ++i2)
#pragma unroll
    for (int j2 = 0; j2 < 2; ++j2) {
      const long gm = m0 + (wr << 7) + i2 * 16 + cm;
      const long gn = n0 + (wc << 5) + j2 * 16 + cn;
      float bv = 0.f;
      if constexpr (EPI >= 1) bv = bias[gn];
#pragma unroll
      for (int r = 0; r < 4; ++r) {
        float v = acc[i2][j2][r] * scale + bv;
        if constexpr (EPI == 2) v = fmaxf(v, 0.f);
        Cb[(gm + r) * ldc + gn] = f2bf(v);
      }
    }
}

// ---------------------------------------------------------------------------
// 64x64 bf16 transpose: Vt[d][s] = V[s][d]
// ---------------------------------------------------------------------------
__global__ __launch_bounds__(256) void transpose_bf16(
    const ushort_t* __restrict__ V, int ldv, long bsV,
    ushort_t* __restrict__ Vt, int ldt, long bsT)
{
  __shared__ __attribute__((aligned(16))) ushort_t tile[64][72];
  const int bz = blockIdx.z;
  const ushort_t* Vb = V + bz * bsV;
  ushort_t* Tb = Vt + bz * bsT;
  const long s0 = (long)blockIdx.y << 6;
  const long d0 = (long)blockIdx.x << 6;
  const int tid = threadIdx.x;
  const int r = tid >> 3, c = tid & 7;
#pragma unroll
  for (int h = 0; h < 2; ++h) {
    const int rr = r + h * 32;
    i32x4 v = *(const i32x4*)(Vb + (s0 + rr) * ldv + d0 + c * 8);
    *(i32x4*)&tile[rr][c * 8] = v;
  }
  __syncthreads();
#pragma unroll
  for (int h = 0; h < 2; ++h) {
    const int dr = r + h * 32;
    union { ushort_t u[8]; i32x4 v; } t;
#pragma unroll
    for (int j = 0; j < 8; ++j) t.u[j] = tile[c * 8 + j][dr];
    *(i32x4*)(Tb + (d0 + dr) * ldt + s0 + c * 8) = t.v;
  }
}

// ---------------------------------------------------------------------------
// Row softmax, register-resident: one short8 per thread covers the whole row.
// Denominator over all s<=t; SIT applied after; zero-fill to 256 boundary.
// ---------------------------------------------------------------------------
__global__ __launch_bounds__(256) void softmax_sit(ushort_t* __restrict__ S,
                                                   const float* __restrict__ sit)
{
  __shared__ float red[4];
  const long row = blockIdx.x;
  const int b = (int)(row >> 11);
  const int t = (int)(row & 2047);
  const int n = t + 1;
  ushort_t* Srow = S + (row << 11);
  const int tid = threadIdx.x;
  const int i0 = tid << 3;

  const u16x8 raw = *(const u16x8*)(Srow + i0);
  float v[8];
#pragma unroll
  for (int j = 0; j < 8; ++j) v[j] = bf2f(raw[j]);

  float mloc = -3.0e38f;
#pragma unroll
  for (int j = 0; j < 8; ++j) if (i0 + j < n) mloc = fmaxf(mloc, v[j]);
#pragma unroll
  for (int o = 32; o > 0; o >>= 1) mloc = fmaxf(mloc, __shfl_down(mloc, o, 64));
  if ((tid & 63) == 0) red[tid >> 6] = mloc;
  __syncthreads();
  const float m = fmaxf(fmaxf(red[0], red[1]), fmaxf(red[2], red[3]));
  __syncthreads();

  float e[8];
  float sloc = 0.f;
#pragma unroll
  for (int j = 0; j < 8; ++j) {
    e[j] = (i0 + j < n) ? __expf(v[j] - m) : 0.f;
    sloc += e[j];
  }
#pragma unroll
  for (int o = 32; o > 0; o >>= 1) sloc += __shfl_down(sloc, o, 64);
  if ((tid & 63) == 0) red[tid >> 6] = sloc;
  __syncthreads();
  const float l = red[0] + red[1] + red[2] + red[3];

  float inv = 1.f / l;
  if (sit[row] == 0.f) inv = 0.f;
  const int rup = ((t >> 8) + 1) << 8;      // matches PV K-limit granularity
  if (i0 < rup) {
    const float* sitb = sit + ((long)b << 11) + i0;
    u16x8 out;
#pragma unroll
    for (int j = 0; j < 8; ++j) {
      const float p = (i0 + j < n && sitb[j] != 0.f) ? e[j] * inv : 0.f;
      out[j] = f2bf(p);
    }
    *(u16x8*)(Srow + i0) = out;
  }
}

// ---------------------------------------------------------------------------
// out = LN(xin + res) * g + b ; D = 1024, one block per row
// ---------------------------------------------------------------------------
template<bool RES_F32, bool OUT_F32>
__global__ __launch_bounds__(256) void resid_ln(
    const ushort_t* __restrict__ xin, const void* __restrict__ resv,
    const float* __restrict__ g, const float* __restrict__ be, void* __restrict__ outv)
{
  __shared__ float red[4];
  const long base = (long)blockIdx.x << 10;
  const int tid = threadIdx.x;
  const int i0 = tid << 2;

  const u16x4 xa = *(const u16x4*)(xin + base + i0);
  float v[4];
  if constexpr (RES_F32) {
    const float4 rv = *(const float4*)((const float*)resv + base + i0);
    v[0] = bf2f(xa.x) + rv.x; v[1] = bf2f(xa.y) + rv.y;
    v[2] = bf2f(xa.z) + rv.z; v[3] = bf2f(xa.w) + rv.w;
  } else {
    const u16x4 rb = *(const u16x4*)((const ushort_t*)resv + base + i0);
    v[0] = bf2f(xa.x) + bf2f(rb.x); v[1] = bf2f(xa.y) + bf2f(rb.y);
    v[2] = bf2f(xa.z) + bf2f(rb.z); v[3] = bf2f(xa.w) + bf2f(rb.w);
  }
  float s = v[0] + v[1] + v[2] + v[3];
#pragma unroll
  for (int o = 32; o > 0; o >>= 1) s += __shfl_down(s, o, 64);
  if ((tid & 63) == 0) red[tid >> 6] = s;
  __syncthreads();
  const float mu = (red[0] + red[1] + red[2] + red[3]) * (1.f / 1024.f);
  __syncthreads();
  float s2 = 0.f;
#pragma unroll
  for (int j = 0; j < 4; ++j) { const float d = v[j] - mu; s2 += d * d; }
#pragma unroll
  for (int o = 32; o > 0; o >>= 1) s2 += __shfl_down(s2, o, 64);
  if ((tid & 63) == 0) red[tid >> 6] = s2;
  __syncthreads();
  const float rstd = rsqrtf((red[0] + red[1] + red[2] + red[3]) * (1.f / 1024.f) + 1e-5f);

  const float4 gv = *(const float4*)(g + i0);
  const float4 bv = *(const float4*)(be + i0);
  const float o0 = (v[0] - mu) * rstd * gv.x + bv.x;
  const float o1 = (v[1] - mu) * rstd * gv.y + bv.y;
  const float o2 = (v[2] - mu) * rstd * gv.z + bv.z;
  const float o3 = (v[3] - mu) * rstd * gv.w + bv.w;
  if constexpr (OUT_F32) {
    float4 ov; ov.x = o0; ov.y = o1; ov.z = o2; ov.w = o3;
    *(float4*)((float*)outv + base + i0) = ov;
  } else {
    u16x4 ob = { f2bf(o0), f2bf(o1), f2bf(o2), f2bf(o3) };
    *(u16x4*)((ushort_t*)outv + base + i0) = ob;
  }
}

__global__ __launch_bounds__(256) void cast_f32_bf16(const float* __restrict__ src,
                                                     ushort_t* __restrict__ dst, int n4)
{
  const int i = blockIdx.x * 256 + threadIdx.x;
  if (i >= n4) return;
  const float4 v = *(const float4*)(src + ((long)i << 2));
  u16x4 o = { f2bf(v.x), f2bf(v.y), f2bf(v.z), f2bf(v.w) };
  *(u16x4*)(dst + ((long)i << 2)) = o;
}

// merged weight casts: 5 x [1024x1024] f32 -> contiguous bf16
__global__ __launch_bounds__(256) void cast_w5(
    const float* __restrict__ s0, const float* __restrict__ s1,
    const float* __restrict__ s2, const float* __restrict__ s3,
    const float* __restrict__ s4, ushort_t* __restrict__ dst)
{
  const int w = blockIdx.y;
  const float* src = (w == 0) ? s0 : (w == 1) ? s1 : (w == 2) ? s2 : (w == 3) ? s3 : s4;
  const long off = (long)w << 20;
  const int i = blockIdx.x * 256 + threadIdx.x;
  const float4 v = *(const float4*)(src + ((long)i << 2));
  u16x4 o = { f2bf(v.x), f2bf(v.y), f2bf(v.z), f2bf(v.w) };
  *(u16x4*)(dst + off + ((long)i << 2)) = o;
}

// ---------------------------------------------------------------------------
// Memory plan (verified green in round 2/3):
//   d_out: [q|k] bf16 -> attb -> final fp32
//   ws R0 (64MiB): [xb|vb] -> S -> [hb|ff1];  R1 (32MiB): vt -> ff2;  R2: weights
// ---------------------------------------------------------------------------
extern "C" void kernel_launch(void* const* d_in, const int* in_sizes, int n_in,
                              void* d_out, int out_size, void* d_ws, size_t ws_size,
                              hipStream_t stream) {
  const int T = 2048, D = 1024;
  const long TD = (long)T * D;
  const long ND = 8 * TD;
  const float* x    = (const float*)d_in[0];
  const float* sit  = (const float*)d_in[1];
  const float* Wq   = (const float*)d_in[2];
  const float* Wk   = (const float*)d_in[3];
  const float* Wv   = (const float*)d_in[4];
  const float* ln1g = (const float*)d_in[5];
  const float* ln1b = (const float*)d_in[6];
  const float* Wf1  = (const float*)d_in[7];
  const float* bf1  = (const float*)d_in[8];
  const float* Wf2  = (const float*)d_in[9];
  const float* bf2  = (const float*)d_in[10];
  const float* ln2g = (const float*)d_in[11];
  const float* ln2b = (const float*)d_in[12];

  ushort_t* W16 = (ushort_t*)d_ws;
  ushort_t* xb  = W16;
  ushort_t* vb  = W16 + ND;
  ushort_t* S   = W16;
  ushort_t* hb  = W16;
  ushort_t* ff1 = W16 + ND;
  ushort_t* vt  = W16 + 2 * ND;
  ushort_t* ff2 = vt;
  ushort_t* wq  = W16 + 3 * ND;
  ushort_t* wk  = wq + (long)D * D;
  ushort_t* wv  = wk + (long)D * D;
  ushort_t* wf1 = wv + (long)D * D;
  ushort_t* wf2 = wf1 + (long)D * D;
  ushort_t* qb = (ushort_t*)d_out;
  ushort_t* kb = qb + ND;
  ushort_t* attb = (ushort_t*)d_out;

  cast_f32_bf16<<<16384, 256, 0, stream>>>(x, xb, (int)(ND / 4));
  cast_w5<<<dim3(1024, 5), 256, 0, stream>>>(Wq, Wk, Wv, Wf1, Wf2, wq);

  // q/k/v projections: 256 blocks each (1/CU), XCD-swizzled
  gemm256<0, true><<<dim3(4, 64), 512, 0, stream>>>(xb, 1024, wq, 1024, qb, 1024, nullptr, 1.f, 1024);
  gemm256<0, true><<<dim3(4, 64), 512, 0, stream>>>(xb, 1024, wk, 1024, kb, 1024, nullptr, 1.f, 1024);
  gemm256<0, true><<<dim3(4, 64), 512, 0, stream>>>(xb, 1024, wv, 1024, vb, 1024, nullptr, 1.f, 1024);

  transpose_bf16<<<dim3(16, 32, 8), 256, 0, stream>>>(vb, 1024, TD, vt, 2048, TD);

  // scores: S = Q K^T / 32, triangular 256x128 tiles (72/batch x 8 = 576)
  gemmA<0, 1, false><<<dim3(576), 512, 0, stream>>>(
      qb, 1024, TD, kb, 1024, TD, S, 2048, (long)T * T, nullptr, 0.03125f, 1024);

  softmax_sit<<<16384, 256, 0, stream>>>(S, sit);

  // att = P @ V (NT via V^T), heavy-first 256x128 tiles, K=(by+1)*256
  gemmA<0, 2, true><<<dim3(512), 512, 0, stream>>>(
      S, 2048, (long)T * T, vt, 2048, TD, attb, 1024, TD, nullptr, 1.f, 2048);

  resid_ln<true, false><<<16384, 256, 0, stream>>>(attb, x, ln1g, ln1b, hb);

  gemm256<2, true><<<dim3(4, 64), 512, 0, stream>>>(hb, 1024, wf1, 1024, ff1, 1024, bf1, 1.f, 1024);
  gemm256<1, true><<<dim3(4, 64), 512, 0, stream>>>(ff1, 1024, wf2, 1024, ff2, 1024, bf2, 1.f, 1024);

  resid_ln<false, true><<<16384, 256, 0, stream>>>(ff2, hb, ln2g, ln2b, (float*)d_out);
}

// Round 5
// 388.734 us; speedup vs baseline: 1.5808x; 1.0330x over previous
//
#include <hip/hip_runtime.h>

typedef unsigned short ushort_t;
typedef __attribute__((ext_vector_type(8))) __bf16 bf16x8;
typedef __attribute__((ext_vector_type(4))) float f32x4;
typedef __attribute__((ext_vector_type(4))) int i32x4;
typedef __attribute__((ext_vector_type(4))) unsigned short u16x4;
typedef __attribute__((ext_vector_type(8))) unsigned short u16x8;

__device__ __forceinline__ float bf2f(ushort_t u) {
  union { unsigned u32; float f; } c; c.u32 = ((unsigned)u) << 16; return c.f;
}
__device__ __forceinline__ ushort_t f2bf(float f) {
  union { float f; unsigned u32; } c; c.f = f;
  unsigned u = c.u32;
  u += 0x7fffu + ((u >> 16) & 1u);
  return (ushort_t)(u >> 16);
}

__device__ __forceinline__ void gload_lds16(const void* g, void* l) {
  __builtin_amdgcn_global_load_lds(
      (const __attribute__((address_space(1))) void*)g,
      (__attribute__((address_space(3))) void*)l,
      16, 0, 0);
}

// Stage one 128x64 bf16 half-tile: linear LDS dest, inverse-swizzled global src
__device__ __forceinline__ void stage_half(const char* gbase, long row0, int ldbytes,
                                           int kbyte, char* lds_half, int tid)
{
  const int rl = tid >> 3;
  const int cs = ((tid & 7) ^ (rl & 7)) << 4;
  const char* g0 = gbase + (row0 + rl) * (long)ldbytes + kbyte + cs;
  char* l0 = lds_half + ((tid >> 6) << 10);
  gload_lds16(g0, l0);
  gload_lds16(g0 + (long)ldbytes * 64, l0 + 8192);
}

#define BAR() __builtin_amdgcn_s_barrier()
#define VMW4() asm volatile("s_waitcnt vmcnt(4)" ::: "memory")
#define VMW2() asm volatile("s_waitcnt vmcnt(2)" ::: "memory")
#define PR1() __builtin_amdgcn_s_setprio(1)
#define PR0() __builtin_amdgcn_s_setprio(0)

#define READ_A(dst, Abase, mb) \
  _Pragma("unroll") for (int m_ = 0; m_ < 4; ++m_) { \
    const char* p_ = (Abase) + ((wr << 7) + (mb) + m_ * 16 + fr) * 128; \
    dst[m_][0] = *(const bf16x8*)(p_ + ch0); \
    dst[m_][1] = *(const bf16x8*)(p_ + ch1); }

// ===========================================================================
// gemm256: 256x256 bf16 NT GEMM, 8-phase (T2 swizzle + T3/T4 + T5).
// BK=64, 8 waves (2Mx4N), per-wave 128x64.
// MAPQ: 1 = 4x64 grid, same-by -> same XCD.  2 = fused-QKV 768-block grid
// (12 bx x 64 by; per XCD: 8 by-panels x all 12 bx).
// ROUTE: epilogue routes bx>>2 -> C0/C1/C2 with local col (bx&3)<<8.
// ===========================================================================
#define READ_B4(dst, Bbase, jb) \
  _Pragma("unroll") for (int n_ = 0; n_ < 2; ++n_) { \
    const char* p_ = (Bbase) + ((wc << 6) + (jb) + n_ * 16 + fr) * 128; \
    dst[n_][0] = *(const bf16x8*)(p_ + ch0); \
    dst[n_][1] = *(const bf16x8*)(p_ + ch1); }

#define MFMA_Q(ib, jb, aarr, barr) \
  _Pragma("unroll") for (int m_ = 0; m_ < 4; ++m_) \
  _Pragma("unroll") for (int n_ = 0; n_ < 2; ++n_) \
  _Pragma("unroll") for (int s_ = 0; s_ < 2; ++s_) \
    acc[(ib) + m_][(jb) + n_] = __builtin_amdgcn_mfma_f32_16x16x32_bf16( \
        aarr[m_][s_], barr[n_][s_], acc[(ib) + m_][(jb) + n_], 0, 0, 0);

#define STAGE_A(t, h, db) stage_half(gA, m0 + (h) * 128, ldab, (t) << 7, \
    (char*)lds + (db) * 32768 + (h) * 16384, tid)
#define STAGE_B(t, h, db) stage_half(gB, n0 + (h) * 128, ldbb, (t) << 7, \
    (char*)lds + 65536 + (db) * 32768 + (h) * 16384, tid)

template<int EPI, int MAPQ, bool ROUTE>
__global__ __launch_bounds__(512, 1) void gemm256(
    const ushort_t* __restrict__ A, int lda,
    const ushort_t* __restrict__ B, int ldb,
    ushort_t* __restrict__ C0, ushort_t* __restrict__ C1, ushort_t* __restrict__ C2,
    int ldc, const float* __restrict__ bias, float scale, int K)
{
  __shared__ __attribute__((aligned(16))) ushort_t lds[65536];

  int bx, by;
  if (MAPQ == 1) {
    const int flat = blockIdx.y * 4 + blockIdx.x;       // grid 4x64
    by = ((flat >> 5) << 3) | (flat & 7);
    bx = (flat >> 3) & 3;
  } else if (MAPQ == 2) {                               // grid 768 linear
    const int l = blockIdx.x;
    const int c = l & 7, u = l >> 3;                    // u 0..95
    const int q12 = u / 12;
    by = (q12 << 3) | c;                                // 0..63, 8 per XCD
    bx = u - q12 * 12;                                  // 0..11
  } else { bx = blockIdx.x; by = blockIdx.y; }

  const int NT = K >> 6;
  const int NIT = NT >> 1, NTm1 = NT - 1;

  const int tid = threadIdx.x;
  const int lane = tid & 63, fr = lane & 15, g = lane >> 4, lm = lane & 7;
  const int wv = tid >> 6, wr = wv >> 2, wc = wv & 3;
  const long m0 = (long)by << 8, n0 = (long)bx << 8;

  const char* gA = (const char*)A;
  const char* gB = (const char*)B;
  const int ldab = lda << 1, ldbb = ldb << 1;

  const int ch0 = (g ^ lm) << 4;
  const int ch1 = ((4 | g) ^ lm) << 4;

  const char* A0 = (const char*)lds;
  const char* A1 = (const char*)lds + 32768;
  const char* B0 = (const char*)lds + 65536;
  const char* B1 = (const char*)lds + 98304;

  f32x4 acc[8][4] = {};
  bf16x8 aF[4][2], aG[4][2], bX[2][2];

  STAGE_A(0, 0, 0); STAGE_A(0, 1, 0); STAGE_B(0, 0, 0); STAGE_B(0, 1, 0);
  STAGE_A(1, 0, 1); STAGE_A(1, 1, 1);
  VMW4(); BAR();

  for (int i = 0; i < NIT; ++i) {
    const int t1 = 2 * i + 1;
    const int t2 = (2 * i + 2 < NTm1) ? 2 * i + 2 : NTm1;
    const int t3 = (2 * i + 3 < NTm1) ? 2 * i + 3 : NTm1;

    READ_A(aF, A0, 0); READ_B4(bX, B0, 0);
    STAGE_B(t1, 0, 1);
    BAR(); PR1(); MFMA_Q(0, 0, aF, bX); PR0(); BAR();

    READ_A(aG, A0, 64);
    STAGE_B(t1, 1, 1);
    BAR(); PR1(); MFMA_Q(4, 0, aG, bX); PR0(); BAR();

    READ_B4(bX, B0, 32);
    STAGE_A(t2, 0, 0);
    BAR(); PR1(); MFMA_Q(4, 2, aG, bX); PR0(); BAR();

    STAGE_A(t2, 1, 0);
    BAR(); PR1(); MFMA_Q(0, 2, aF, bX); PR0(); VMW4(); BAR();

    READ_A(aF, A1, 0); READ_B4(bX, B1, 0);
    STAGE_B(t2, 0, 0);
    BAR(); PR1(); MFMA_Q(0, 0, aF, bX); PR0(); BAR();

    READ_A(aG, A1, 64);
    STAGE_B(t2, 1, 0);
    BAR(); PR1(); MFMA_Q(4, 0, aG, bX); PR0(); BAR();

    READ_B4(bX, B1, 32);
    STAGE_A(t3, 0, 1);
    BAR(); PR1(); MFMA_Q(4, 2, aG, bX); PR0(); BAR();

    STAGE_A(t3, 1, 1);
    BAR(); PR1(); MFMA_Q(0, 2, aF, bX); PR0(); VMW4(); BAR();
  }

  ushort_t* Cd = C0;
  long nc0 = (long)bx << 8;
  if constexpr (ROUTE) {
    const int which = bx >> 2;
    Cd = (which == 0) ? C0 : (which == 1) ? C1 : C2;
    nc0 = (long)(bx & 3) << 8;
  }

  const int cm = g << 2, cn = fr;
#pragma unroll
  for (int i2 = 0; i2 < 8; ++i2)
#pragma unroll
    for (int j2 = 0; j2 < 4; ++j2) {
      const long gm = m0 + (wr << 7) + i2 * 16 + cm;
      const long gn = nc0 + (wc << 6) + j2 * 16 + cn;
      float bv = 0.f;
      if constexpr (EPI >= 1) bv = bias[gn];
#pragma unroll
      for (int r = 0; r < 4; ++r) {
        float v = acc[i2][j2][r] * scale + bv;
        if constexpr (EPI == 2) v = fmaxf(v, 0.f);
        Cd[(gm + r) * ldc + gn] = f2bf(v);
      }
    }
}

// ===========================================================================
// gemmA: 256x128 bf16 NT GEMM, 4-phase per 2 K-tiles, VMW(2) cadence.
// LDS 96 KiB. Per-wave out 128x32.  Both maps pin batch bz = bid&7 -> XCD.
// MAP: 1 = triangular scores grid (72 tiles/batch, grid=576),
//      2 = heavy-first PV grid (64 tiles/batch, grid=512), K=(by+1)*256.
// ===========================================================================
#define READ_B2(dst, Bbase) \
  _Pragma("unroll") for (int n_ = 0; n_ < 2; ++n_) { \
    const char* p_ = (Bbase) + ((wc << 5) + n_ * 16 + fr) * 128; \
    dst[n_][0] = *(const bf16x8*)(p_ + ch0); \
    dst[n_][1] = *(const bf16x8*)(p_ + ch1); }

#define MFMA_H(ib, aarr) \
  _Pragma("unroll") for (int m_ = 0; m_ < 4; ++m_) \
  _Pragma("unroll") for (int n_ = 0; n_ < 2; ++n_) \
  _Pragma("unroll") for (int s_ = 0; s_ < 2; ++s_) \
    acc[(ib) + m_][n_] = __builtin_amdgcn_mfma_f32_16x16x32_bf16( \
        aarr[m_][s_], bX[n_][s_], acc[(ib) + m_][n_], 0, 0, 0);

#define SA_(t, h, db) stage_half(gA, m0 + (h) * 128, ldab, (t) << 7, \
    (char*)lds + (db) * 32768 + (h) * 16384, tid)
#define SB_(t, db) stage_half(gB, n0, ldbb, (t) << 7, \
    (char*)lds + 65536 + (db) * 16384, tid)

template<int EPI, int MAP, bool CKLIM>
__global__ __launch_bounds__(512, 1) void gemmA(
    const ushort_t* __restrict__ A, int lda, long bsA,
    const ushort_t* __restrict__ B, int ldb, long bsB,
    ushort_t* __restrict__ C, int ldc, long bsC,
    const float* __restrict__ bias, float scale, int K)
{
  __shared__ __attribute__((aligned(16))) ushort_t lds[49152];  // 96 KiB

  int bx, by, bz;
  if (MAP == 1) {            // scores: bz pinned to XCD, triangular within
    const int bid = blockIdx.x;
    bz = bid & 7; const int r = bid >> 3;            // r 0..71
    by = 0; while ((by + 1) * (by + 2) <= r) ++by;
    bx = r - by * (by + 1);
  } else if (MAP == 2) {     // PV: bz pinned to XCD, heavy-first within
    const int bid = blockIdx.x;
    bz = bid & 7; const int u = bid >> 3;            // u 0..63
    by = 7 - (u >> 3); bx = u & 7;
  } else { bx = blockIdx.x; by = blockIdx.y; bz = blockIdx.z; }

  const int NT = CKLIM ? ((by + 1) << 2) : (K >> 6);
  const int NIT = NT >> 1, NTm1 = NT - 1;

  const int tid = threadIdx.x;
  const int lane = tid & 63, fr = lane & 15, g = lane >> 4, lm = lane & 7;
  const int wv = tid >> 6, wr = wv >> 2, wc = wv & 3;
  const long m0 = (long)by << 8, n0 = (long)bx << 7;

  const char* gA = (const char*)(A + bz * bsA);
  const char* gB = (const char*)(B + bz * bsB);
  const int ldab = lda << 1, ldbb = ldb << 1;

  const int ch0 = (g ^ lm) << 4;
  const int ch1 = ((4 | g) ^ lm) << 4;

  const char* A0b = (const char*)lds;
  const char* A1b = (const char*)lds + 32768;
  const char* B0b = (const char*)lds + 65536;
  const char* B1b = (const char*)lds + 81920;

  f32x4 acc[8][2] = {};
  bf16x8 aF[4][2], aG[4][2], bX[2][2];

  SA_(0, 0, 0); SA_(0, 1, 0); SB_(0, 0); SB_(1, 1);
  VMW2(); BAR();

  for (int i = 0; i < NIT; ++i) {
    const int o = 2 * i + 1;
    const int t2 = (2 * i + 2 < NTm1) ? 2 * i + 2 : NTm1;
    const int t3 = (2 * i + 3 < NTm1) ? 2 * i + 3 : NTm1;

    READ_A(aF, A0b, 0); READ_B2(bX, B0b);
    SA_(o, 0, 1); SA_(o, 1, 1);
    BAR(); PR1(); MFMA_H(0, aF); PR0(); BAR();

    READ_A(aG, A0b, 64);
    SB_(t2, 0);
    BAR(); PR1(); MFMA_H(4, aG); PR0(); VMW2(); BAR();

    READ_A(aF, A1b, 0); READ_B2(bX, B1b);
    SA_(t2, 0, 0);
    BAR(); PR1(); MFMA_H(0, aF); PR0(); BAR();

    READ_A(aG, A1b, 64);
    SA_(t2, 1, 0);
    SB_(t3, 1);
    BAR(); PR1(); MFMA_H(4, aG); PR0(); VMW2(); BAR();
  }

  ushort_t* Cb = C + bz * bsC;
  const int cm = g << 2, cn = fr;
#pragma unroll
  for (int i2 = 0; i2 < 8; ++i2)
#pragma unroll
    for (int j2 = 0; j2 < 2; ++j2) {
      const long gm = m0 + (wr << 7) + i2 * 16 + cm;
      const long gn = n0 + (wc << 5) + j2 * 16 + cn;
      float bv = 0.f;
      if constexpr (EPI >= 1) bv = bias[gn];
#pragma unroll
      for (int r = 0; r < 4; ++r) {
        float v = acc[i2][j2][r] * scale + bv;
        if constexpr (EPI == 2) v = fmaxf(v, 0.f);
        Cb[(gm + r) * ldc + gn] = f2bf(v);
      }
    }
}

// ---------------------------------------------------------------------------
// 64x64 bf16 transpose: Vt[d][s] = V[s][d]
// ---------------------------------------------------------------------------
__global__ __launch_bounds__(256) void transpose_bf16(
    const ushort_t* __restrict__ V, int ldv, long bsV,
    ushort_t* __restrict__ Vt, int ldt, long bsT)
{
  __shared__ __attribute__((aligned(16))) ushort_t tile[64][72];
  const int bz = blockIdx.z;
  const ushort_t* Vb = V + bz * bsV;
  ushort_t* Tb = Vt + bz * bsT;
  const long s0 = (long)blockIdx.y << 6;
  const long d0 = (long)blockIdx.x << 6;
  const int tid = threadIdx.x;
  const int r = tid >> 3, c = tid & 7;
#pragma unroll
  for (int h = 0; h < 2; ++h) {
    const int rr = r + h * 32;
    i32x4 v = *(const i32x4*)(Vb + (s0 + rr) * ldv + d0 + c * 8);
    *(i32x4*)&tile[rr][c * 8] = v;
  }
  __syncthreads();
#pragma unroll
  for (int h = 0; h < 2; ++h) {
    const int dr = r + h * 32;
    union { ushort_t u[8]; i32x4 v; } t;
#pragma unroll
    for (int j = 0; j < 8; ++j) t.u[j] = tile[c * 8 + j][dr];
    *(i32x4*)(Tb + (d0 + dr) * ldt + s0 + c * 8) = t.v;
  }
}

// ---------------------------------------------------------------------------
// Row softmax, register-resident (one short8/thread = whole 2048 row).
// ---------------------------------------------------------------------------
__global__ __launch_bounds__(256) void softmax_sit(ushort_t* __restrict__ S,
                                                   const float* __restrict__ sit)
{
  __shared__ float red[4];
  const long row = blockIdx.x;
  const int b = (int)(row >> 11);
  const int t = (int)(row & 2047);
  const int n = t + 1;
  ushort_t* Srow = S + (row << 11);
  const int tid = threadIdx.x;
  const int i0 = tid << 3;

  const u16x8 raw = *(const u16x8*)(Srow + i0);
  float v[8];
#pragma unroll
  for (int j = 0; j < 8; ++j) v[j] = bf2f(raw[j]);

  float mloc = -3.0e38f;
#pragma unroll
  for (int j = 0; j < 8; ++j) if (i0 + j < n) mloc = fmaxf(mloc, v[j]);
#pragma unroll
  for (int o = 32; o > 0; o >>= 1) mloc = fmaxf(mloc, __shfl_down(mloc, o, 64));
  if ((tid & 63) == 0) red[tid >> 6] = mloc;
  __syncthreads();
  const float m = fmaxf(fmaxf(red[0], red[1]), fmaxf(red[2], red[3]));
  __syncthreads();

  float e[8];
  float sloc = 0.f;
#pragma unroll
  for (int j = 0; j < 8; ++j) {
    e[j] = (i0 + j < n) ? __expf(v[j] - m) : 0.f;
    sloc += e[j];
  }
#pragma unroll
  for (int o = 32; o > 0; o >>= 1) sloc += __shfl_down(sloc, o, 64);
  if ((tid & 63) == 0) red[tid >> 6] = sloc;
  __syncthreads();
  const float l = red[0] + red[1] + red[2] + red[3];

  float inv = 1.f / l;
  if (sit[row] == 0.f) inv = 0.f;
  const int rup = ((t >> 8) + 1) << 8;
  if (i0 < rup) {
    const float* sitb = sit + ((long)b << 11) + i0;
    u16x8 out;
#pragma unroll
    for (int j = 0; j < 8; ++j) {
      const float p = (i0 + j < n && sitb[j] != 0.f) ? e[j] * inv : 0.f;
      out[j] = f2bf(p);
    }
    *(u16x8*)(Srow + i0) = out;
  }
}

// ---------------------------------------------------------------------------
// out = LN(xin + res) * g + b ; D = 1024, one block per row
// ---------------------------------------------------------------------------
template<bool RES_F32, bool OUT_F32>
__global__ __launch_bounds__(256) void resid_ln(
    const ushort_t* __restrict__ xin, const void* __restrict__ resv,
    const float* __restrict__ g, const float* __restrict__ be, void* __restrict__ outv)
{
  __shared__ float red[4];
  const long base = (long)blockIdx.x << 10;
  const int tid = threadIdx.x;
  const int i0 = tid << 2;

  const u16x4 xa = *(const u16x4*)(xin + base + i0);
  float v[4];
  if constexpr (RES_F32) {
    const float4 rv = *(const float4*)((const float*)resv + base + i0);
    v[0] = bf2f(xa.x) + rv.x; v[1] = bf2f(xa.y) + rv.y;
    v[2] = bf2f(xa.z) + rv.z; v[3] = bf2f(xa.w) + rv.w;
  } else {
    const u16x4 rb = *(const u16x4*)((const ushort_t*)resv + base + i0);
    v[0] = bf2f(xa.x) + bf2f(rb.x); v[1] = bf2f(xa.y) + bf2f(rb.y);
    v[2] = bf2f(xa.z) + bf2f(rb.z); v[3] = bf2f(xa.w) + bf2f(rb.w);
  }
  float s = v[0] + v[1] + v[2] + v[3];
#pragma unroll
  for (int o = 32; o > 0; o >>= 1) s += __shfl_down(s, o, 64);
  if ((tid & 63) == 0) red[tid >> 6] = s;
  __syncthreads();
  const float mu = (red[0] + red[1] + red[2] + red[3]) * (1.f / 1024.f);
  __syncthreads();
  float s2 = 0.f;
#pragma unroll
  for (int j = 0; j < 4; ++j) { const float d = v[j] - mu; s2 += d * d; }
#pragma unroll
  for (int o = 32; o > 0; o >>= 1) s2 += __shfl_down(s2, o, 64);
  if ((tid & 63) == 0) red[tid >> 6] = s2;
  __syncthreads();
  const float rstd = rsqrtf((red[0] + red[1] + red[2] + red[3]) * (1.f / 1024.f) + 1e-5f);

  const float4 gv = *(const float4*)(g + i0);
  const float4 bv = *(const float4*)(be + i0);
  const float o0 = (v[0] - mu) * rstd * gv.x + bv.x;
  const float o1 = (v[1] - mu) * rstd * gv.y + bv.y;
  const float o2 = (v[2] - mu) * rstd * gv.z + bv.z;
  const float o3 = (v[3] - mu) * rstd * gv.w + bv.w;
  if constexpr (OUT_F32) {
    float4 ov; ov.x = o0; ov.y = o1; ov.z = o2; ov.w = o3;
    *(float4*)((float*)outv + base + i0) = ov;
  } else {
    u16x4 ob = { f2bf(o0), f2bf(o1), f2bf(o2), f2bf(o3) };
    *(u16x4*)((ushort_t*)outv + base + i0) = ob;
  }
}

__global__ __launch_bounds__(256) void cast_f32_bf16(const float* __restrict__ src,
                                                     ushort_t* __restrict__ dst, int n4)
{
  const int i = blockIdx.x * 256 + threadIdx.x;
  if (i >= n4) return;
  const float4 v = *(const float4*)(src + ((long)i << 2));
  u16x4 o = { f2bf(v.x), f2bf(v.y), f2bf(v.z), f2bf(v.w) };
  *(u16x4*)(dst + ((long)i << 2)) = o;
}

__global__ __launch_bounds__(256) void cast_w5(
    const float* __restrict__ s0, const float* __restrict__ s1,
    const float* __restrict__ s2, const float* __restrict__ s3,
    const float* __restrict__ s4, ushort_t* __restrict__ dst)
{
  const int w = blockIdx.y;
  const float* src = (w == 0) ? s0 : (w == 1) ? s1 : (w == 2) ? s2 : (w == 3) ? s3 : s4;
  const long off = (long)w << 20;
  const int i = blockIdx.x * 256 + threadIdx.x;
  const float4 v = *(const float4*)(src + ((long)i << 2));
  u16x4 o = { f2bf(v.x), f2bf(v.y), f2bf(v.z), f2bf(v.w) };
  *(u16x4*)(dst + off + ((long)i << 2)) = o;
}

// ---------------------------------------------------------------------------
// Memory plan (green since round 2):
//   d_out: [q|k] bf16 -> attb -> final fp32
//   ws R0 (64MiB): [xb|vb] -> S -> [hb|ff1];  R1 (32MiB): vt -> ff2;  R2: weights
// ---------------------------------------------------------------------------
extern "C" void kernel_launch(void* const* d_in, const int* in_sizes, int n_in,
                              void* d_out, int out_size, void* d_ws, size_t ws_size,
                              hipStream_t stream) {
  const int T = 2048, D = 1024;
  const long TD = (long)T * D;
  const long ND = 8 * TD;
  const float* x    = (const float*)d_in[0];
  const float* sit  = (const float*)d_in[1];
  const float* Wq   = (const float*)d_in[2];
  const float* Wk   = (const float*)d_in[3];
  const float* Wv   = (const float*)d_in[4];
  const float* ln1g = (const float*)d_in[5];
  const float* ln1b = (const float*)d_in[6];
  const float* Wf1  = (const float*)d_in[7];
  const float* bf1  = (const float*)d_in[8];
  const float* Wf2  = (const float*)d_in[9];
  const float* bf2  = (const float*)d_in[10];
  const float* ln2g = (const float*)d_in[11];
  const float* ln2b = (const float*)d_in[12];

  ushort_t* W16 = (ushort_t*)d_ws;
  ushort_t* xb  = W16;
  ushort_t* vb  = W16 + ND;
  ushort_t* S   = W16;
  ushort_t* hb  = W16;
  ushort_t* ff1 = W16 + ND;
  ushort_t* vt  = W16 + 2 * ND;
  ushort_t* ff2 = vt;
  ushort_t* wq  = W16 + 3 * ND;      // wq|wk|wv contiguous = fused [3072][1024]
  ushort_t* wf1 = wq + 3L * D * D;
  ushort_t* wf2 = wf1 + (long)D * D;
  ushort_t* qb = (ushort_t*)d_out;
  ushort_t* kb = qb + ND;
  ushort_t* attb = (ushort_t*)d_out;

  cast_f32_bf16<<<16384, 256, 0, stream>>>(x, xb, (int)(ND / 4));
  cast_w5<<<dim3(1024, 5), 256, 0, stream>>>(Wq, Wk, Wv, Wf1, Wf2, wq);

  // fused QKV: [16384,1024] @ [3072,1024]^T, epilogue routes to qb/kb/vb
  gemm256<0, 2, true><<<dim3(768), 512, 0, stream>>>(
      xb, 1024, wq, 1024, qb, kb, vb, 1024, nullptr, 1.f, 1024);

  transpose_bf16<<<dim3(16, 32, 8), 256, 0, stream>>>(vb, 1024, TD, vt, 2048, TD);

  // scores: S = Q K^T / 32, batch->XCD pinned triangular 256x128 tiles
  gemmA<0, 1, false><<<dim3(576), 512, 0, stream>>>(
      qb, 1024, TD, kb, 1024, TD, S, 2048, (long)T * T, nullptr, 0.03125f, 1024);

  softmax_sit<<<16384, 256, 0, stream>>>(S, sit);

  // att = P @ V, batch->XCD pinned heavy-first tiles, K=(by+1)*256
  gemmA<0, 2, true><<<dim3(512), 512, 0, stream>>>(
      S, 2048, (long)T * T, vt, 2048, TD, attb, 1024, TD, nullptr, 1.f, 2048);

  resid_ln<true, false><<<16384, 256, 0, stream>>>(attb, x, ln1g, ln1b, hb);

  gemm256<2, 1, false><<<dim3(4, 64), 512, 0, stream>>>(
      hb, 1024, wf1, 1024, ff1, ff1, ff1, 1024, bf1, 1.f, 1024);
  gemm256<1, 1, false><<<dim3(4, 64), 512, 0, stream>>>(
      ff1, 1024, wf2, 1024, ff2, ff2, ff2, 1024, bf2, 1.f, 1024);

  resid_ln<false, true><<<16384, 256, 0, stream>>>(ff2, hb, ln2g, ln2b, (float*)d_out);
}